// Round 9
// baseline (386.421 us; speedup 1.0000x reference)
//
#include <hip/hip_runtime.h>
#include <math.h>

#define EPSBN 1e-5f

typedef _Float16 f16x8 __attribute__((ext_vector_type(8)));
typedef _Float16 f16x2 __attribute__((ext_vector_type(2)));
typedef float    f32x4 __attribute__((ext_vector_type(4)));

__device__ __forceinline__ f16x8 splat8(float v) {
  _Float16 h = (_Float16)v;
  return (f16x8){h, h, h, h, h, h, h, h};
}

// ---------------- workspace layout (float-unit offsets) — validated ----------
static constexpr size_t XF_EX = 0;         // (16,20,20,256) f16
static constexpr size_t XF_IN = 819200;    // (16,32,32,256) f16
static constexpr size_t WPK   = 2916352;   // dcn_w f16 frag pack
static constexpr size_t OWPK  = 4096000;   // off_w f16 frag pack
static constexpr size_t FWT   = 4243456;   // (2,256,256) f32
static constexpr size_t HOUT0 = 5432064;   // (16,256,324) f32
static constexpr size_t HOUT1 = 6759168;   // (16,256,900) f32
static constexpr size_t HOUT2 = 10445568;
static constexpr size_t HOUT3 = 11772672;
static constexpr size_t XCB   = 15459072;  // (2,16,256,169) f32
// end 18227968 floats = 72.9 MB

// ---------------- NCHW fp32 -> NHWC f16 ----------------
__global__ __launch_bounds__(256) void k_transpose(const float* __restrict__ in,
                                                   _Float16* __restrict__ out,
                                                   int H, int W) {
  int y = blockIdx.x, b = blockIdx.y;
  __shared__ float tile[32][257];
  int t = threadIdx.x;
  int x = t & 31, cb = t >> 5;
  for (int c0 = 0; c0 < 256; c0 += 8) {
    int c = c0 + cb;
    if (x < W) tile[x][c] = in[(((size_t)b * 256 + c) * H + y) * W + x];
  }
  __syncthreads();
  for (int x2 = 0; x2 < W; ++x2)
    out[((((size_t)b * H + y) * W + x2) << 8) + t] = (_Float16)tile[x2][t];
}

// ---------------- dcn_w -> f16 MFMA-A fragment pack (validated) --------------
__global__ __launch_bounds__(256) void k_wpack(const float* __restrict__ w,
                                               _Float16* __restrict__ wp) {
  int idx = blockIdx.x * 256 + threadIdx.x;
  if (idx >= 4 * 9 * 8 * 16 * 64 * 8) return;
  int e  = idx & 7;
  int l  = (idx >> 3) & 63;
  int ot = (idx >> 9) & 15;
  int cs = (idx >> 13) & 7;
  int ht = idx >> 16;             // h*9 + tap
  int tap = ht % 9, h = ht / 9;
  int o = ot * 16 + (l & 15);
  int c = cs * 32 + 8 * (l >> 4) + e;
  wp[idx] = (_Float16)w[((size_t)((h * 256 + o) * 256 + c)) * 9 + tap];
}

// ---------------- off_w -> f16 MFMA-A fragment pack (M=27 padded to 32) ------
__global__ __launch_bounds__(256) void k_owpack(const float* __restrict__ w,
                                                _Float16* __restrict__ wp) {
  int idx = blockIdx.x * 256 + threadIdx.x;
  if (idx >= 4 * 9 * 8 * 2 * 64 * 8) return;
  int e  = idx & 7;
  int l  = (idx >> 3) & 63;
  int ot = (idx >> 9) & 1;
  int cs = (idx >> 10) & 7;
  int ht = idx >> 13;
  int tap = ht % 9, h = ht / 9;
  int o = ot * 16 + (l & 15);
  int c = cs * 32 + 8 * (l >> 4) + e;
  wp[idx] = (o < 27) ? (_Float16)w[((size_t)((h * 27 + o) * 256 + c)) * 9 + tap]
                     : (_Float16)0.f;
}

// ---------------- fus_w (2,256,256)[i][o][c] -> fwt [i][c][o] (fp32) ---------
__global__ __launch_bounds__(256) void k_fwt(const float* __restrict__ w,
                                             float* __restrict__ wt) {
  int idx = blockIdx.x * 256 + threadIdx.x;
  int o = idx & 255, c = (idx >> 8) & 255, i = idx >> 16;
  wt[idx] = w[(i << 16) + (o << 8) + c];
}

// ---------------- fused head: offset conv (MFMA, om in LDS) + deform GEMM ----
// 512 thr; h-major 1D grid (96 + 240 + 96 + 240 = 672 blocks)
__global__ __launch_bounds__(512, 4) void k_head(const _Float16* __restrict__ xh_ex,
                                                 const _Float16* __restrict__ xh_in,
                                                 const _Float16* __restrict__ owpk,
                                                 const _Float16* __restrict__ wpk,
                                                 const float* __restrict__ off_b,
                                                 float* __restrict__ ws,
                                                 const float* __restrict__ dcn_b,
                                                 const float* __restrict__ g1,
                                                 const float* __restrict__ b1,
                                                 const float* __restrict__ m1,
                                                 const float* __restrict__ v1) {
  // decode h-major block index: per h, b-major then tile
  int idx = blockIdx.x;
  int h, b, tl;
  if (idx < 96)       { h = 0; b = idx / 6;              tl = idx - 6 * b; }
  else if (idx < 336) { h = 1; int r = idx - 96;  b = r / 15; tl = r - 15 * b; }
  else if (idx < 432) { h = 2; int r = idx - 336; b = r / 6;  tl = r - 6 * b; }
  else                { h = 3; int r = idx - 432; b = r / 15; tl = r - 15 * b; }
  const int HH4[4] = {20, 32, 20, 32};
  const size_t HOO[4] = {HOUT0, HOUT1, HOUT2, HOUT3};
  const int H = HH4[h], W = H, ho = H - 2, wo = W - 2, P = ho * wo;
  const int p0 = tl << 6;
  const _Float16* xh  = (h & 1) ? xh_in : xh_ex;          // no b offset (abs addrs)
  const _Float16* xhb = xh + (((size_t)b * H * W) << 8);  // b-local for off conv
  float* outp = ws + HOO[h] + (size_t)b * 256 * P;

  __shared__ __align__(16) _Float16 S[64 * 256];
  __shared__ float4 swt4[576];
  __shared__ int4   sad4[576];
  __shared__ float  om_l[27][65];
  __shared__ int    rowoff[64];

  const int t = threadIdx.x, lane = t & 63, wave = t >> 6;
  const int o8 = t & 31, plb = t >> 5;      // o8: 8-ch group; plb: pixel 0..15
  const int ot = wave & 1, nn = wave >> 1;

  if (t < 64) {
    int p = min(p0 + t, P - 1);
    int i = p / wo, j = p - i * wo;
    rowoff[t] = (i * W + j) << 8;
  }
  __syncthreads();

  // ================= offset-conv phase (om stays in LDS) =================
  f32x4 accO = {0.f, 0.f, 0.f, 0.f};
  f16x8 gr[4];
  #pragma unroll
  for (int it = 0; it < 4; ++it) {          // preload tap 0
    int pl = it * 16 + plb;
    gr[it] = *(const f16x8*)(xhb + rowoff[pl] + o8 * 8);
  }
  for (int tap = 0; tap < 9; ++tap) {
    #pragma unroll
    for (int it = 0; it < 4; ++it) {
      int pl = it * 16 + plb;
      *(f16x8*)((char*)S + pl * 512 + ((o8 * 16) ^ ((pl & 7) << 4))) = gr[it];
    }
    __syncthreads();
    if (tap < 8) {                          // prefetch next raw tile
      int ky = (tap + 1) / 3, kx = (tap + 1) - ky * 3;
      int koff = (ky * W + kx) << 8;
      #pragma unroll
      for (int it = 0; it < 4; ++it) {
        int pl = it * 16 + plb;
        gr[it] = *(const f16x8*)(xhb + rowoff[pl] + koff + o8 * 8);
      }
    }
    #pragma unroll
    for (int cs = 0; cs < 8; ++cs) {
      int ksg = tap * 8 + cs;
      f16x8 a = *(const f16x8*)(owpk + ((size_t)((h * 72 + ksg) * 2 + ot)) * 512 + lane * 8);
      int prow = nn * 16 + (lane & 15);
      f16x8 bf = *(const f16x8*)((char*)S + prow * 512 +
                                 ((cs * 64 + ((lane >> 4) << 4)) ^ ((prow & 7) << 4)));
      accO = __builtin_amdgcn_mfma_f32_16x16x32_f16(a, bf, accO, 0, 0, 0);
    }
    __syncthreads();
  }
  {
    int pcol = nn * 16 + (lane & 15);
    #pragma unroll
    for (int r = 0; r < 4; ++r) {
      int o = ot * 16 + 4 * (lane >> 4) + r;
      if (o < 27) om_l[o][pcol] = accO[r] + off_b[h * 27 + o];
    }
  }
  __syncthreads();

  // ================= Phase A: bilinear tables from LDS om =================
  for (int e = t; e < 576; e += 512) {
    int pl = e / 9, k = e - pl * 9;
    float w4[4] = {0.f, 0.f, 0.f, 0.f};
    int a4[4] = {0, 0, 0, 0};
    int p = p0 + pl;
    if (p < P) {
      int i = p / wo, j = p - i * wo;
      float oy = om_l[2 * k][pl];
      float ox = om_l[2 * k + 1][pl];
      float mm = om_l[18 + k][pl];
      float msk = 1.f / (1.f + __expf(-mm));
      int ky = k / 3, kx = k - ky * 3;
      float py = (float)(ky + i) + oy;
      float px = (float)(kx + j) + ox;
      float fy = floorf(py), fx = floorf(px);
      int y0 = (int)fy, x0 = (int)fx;
      float dy = py - fy, dx = px - fx;
      #pragma unroll
      for (int q = 0; q < 4; ++q) {
        int yy = y0 + (q >> 1), xx = x0 + (q & 1);
        bool vld = (yy >= 0) && (yy < H) && (xx >= 0) && (xx < W);
        int yc = min(max(yy, 0), H - 1), xc = min(max(xx, 0), W - 1);
        float wq = ((q >> 1) ? dy : 1.f - dy) * ((q & 1) ? dx : 1.f - dx);
        w4[q] = vld ? wq * msk : 0.f;
        a4[q] = ((b * H + yc) * W + xc) << 8;
      }
    }
    swt4[e] = make_float4(w4[0], w4[1], w4[2], w4[3]);
    sad4[e] = make_int4(a4[0], a4[1], a4[2], a4[3]);
  }

  f32x4 acc[2][4];
  #pragma unroll
  for (int a = 0; a < 2; ++a)
    #pragma unroll
    for (int n = 0; n < 4; ++n) acc[a][n] = (f32x4){0.f, 0.f, 0.f, 0.f};
  __syncthreads();

  // ================= main deform GEMM with gather prefetch =================
  const _Float16* xb = xh + o8 * 8;
  f16x8 gx[16];
  #pragma unroll
  for (int it = 0; it < 4; ++it) {          // preload tap 0 gathers (16 loads)
    int e = (it * 16 + plb) * 9;
    int4 a4 = sad4[e];
    gx[it * 4 + 0] = *(const f16x8*)(xb + a4.x);
    gx[it * 4 + 1] = *(const f16x8*)(xb + a4.y);
    gx[it * 4 + 2] = *(const f16x8*)(xb + a4.z);
    gx[it * 4 + 3] = *(const f16x8*)(xb + a4.w);
  }
  for (int tap = 0; tap < 9; ++tap) {
    // combine (fma chain -> v_pk_fma) + swizzled LDS write
    #pragma unroll
    for (int it = 0; it < 4; ++it) {
      int pl = it * 16 + plb;
      float4 w4 = swt4[pl * 9 + tap];
      f16x8 s = gx[it * 4 + 0] * splat8(w4.x);
      s = gx[it * 4 + 1] * splat8(w4.y) + s;
      s = gx[it * 4 + 2] * splat8(w4.z) + s;
      s = gx[it * 4 + 3] * splat8(w4.w) + s;
      *(f16x8*)((char*)S + pl * 512 + ((o8 * 16) ^ ((pl & 7) << 4))) = s;
    }
    __syncthreads();
    if (tap < 8) {                          // prefetch next tap's gathers
      #pragma unroll
      for (int it = 0; it < 4; ++it) {
        int e = (it * 16 + plb) * 9 + tap + 1;
        int4 a4 = sad4[e];
        gx[it * 4 + 0] = *(const f16x8*)(xb + a4.x);
        gx[it * 4 + 1] = *(const f16x8*)(xb + a4.y);
        gx[it * 4 + 2] = *(const f16x8*)(xb + a4.z);
        gx[it * 4 + 3] = *(const f16x8*)(xb + a4.w);
      }
    }
    #pragma unroll
    for (int cs = 0; cs < 8; ++cs) {
      int ksg = tap * 8 + cs;
      const _Float16* ab = wpk + ((size_t)(h * 72 + ksg) * 16 + wave * 2) * 512 + lane * 8;
      f16x8 A0 = *(const f16x8*)(ab);
      f16x8 A1 = *(const f16x8*)(ab + 512);
      f16x8 B[4];
      #pragma unroll
      for (int n = 0; n < 4; ++n) {
        int prow = n * 16 + (lane & 15);
        B[n] = *(const f16x8*)((char*)S + prow * 512 +
                               ((cs * 64 + ((lane >> 4) << 4)) ^ ((prow & 7) << 4)));
      }
      #pragma unroll
      for (int n = 0; n < 4; ++n) {
        acc[0][n] = __builtin_amdgcn_mfma_f32_16x16x32_f16(A0, B[n], acc[0][n], 0, 0, 0);
        acc[1][n] = __builtin_amdgcn_mfma_f32_16x16x32_f16(A1, B[n], acc[1][n], 0, 0, 0);
      }
    }
    __syncthreads();
  }

  // epilogue: + dcn_b then bn1; out layout (B,256o,P) fp32 (validated)
  #pragma unroll
  for (int a = 0; a < 2; ++a) {
    int obase = (wave * 2 + a) * 16 + 4 * (lane >> 4);
    #pragma unroll
    for (int r = 0; r < 4; ++r) {
      int o = obase + r;
      float al = g1[h * 256 + o] * rsqrtf(v1[h * 256 + o] + EPSBN);
      float be = (dcn_b[h * 256 + o] - m1[h * 256 + o]) * al + b1[h * 256 + o];
      #pragma unroll
      for (int n = 0; n < 4; ++n) {
        int p = p0 + n * 16 + (lane & 15);
        if (p < P) outp[(size_t)o * P + p] = fmaf(acc[a][n][r], al, be);
      }
    }
  }
}

// ---------------- xcorr v3 (validated round-7) -------------------------------
__global__ __launch_bounds__(256) void k_xcorr3(float* __restrict__ ws) {
  const int br = blockIdx.y;
  const int bc0 = blockIdx.x << 4;
  const float* exg = ws + (br ? HOUT2 : HOUT0) + (size_t)bc0 * 324;
  const float* ing = ws + (br ? HOUT3 : HOUT1) + (size_t)bc0 * 900;
  __shared__ __align__(16) _Float16 exl[16 * 324];
  __shared__ __align__(16) _Float16 inl[16 * 960];   // rows padded 30 -> 32
  const int t = threadIdx.x;
  for (int idx = t; idx < 16 * 324; idx += 256)
    exl[idx] = (_Float16)exg[idx];
  for (int idx = t; idx < 16 * 960; idx += 256) {
    int c = idx & 31;
    int rr = idx >> 5;
    inl[idx] = (c < 30) ? (_Float16)ing[rr * 30 + c] : (_Float16)0.f;
  }
  __syncthreads();
  const int lane = t & 63, wave = t >> 6;
  const int sub = lane / 13;
  const int i = lane - sub * 13;
  const bool active = sub < 4;
  const int bcl = wave * 4 + (active ? sub : 0);
  float acc[13];
  #pragma unroll
  for (int j = 0; j < 13; ++j) acc[j] = 0.f;
  const _Float16* inb = inl + bcl * 960;
  const _Float16* exb = exl + bcl * 324;
  for (int u = 0; u < 18; ++u) {
    float a[30];
    const _Float16* rp = inb + (i + u) * 32;
    #pragma unroll
    for (int x = 0; x < 15; ++x) {
      f16x2 pr = *(const f16x2*)(rp + 2 * x);
      a[2 * x] = (float)pr[0]; a[2 * x + 1] = (float)pr[1];
    }
    float e[18];
    const _Float16* ep = exb + u * 18;
    #pragma unroll
    for (int x = 0; x < 9; ++x) {
      f16x2 pr = *(const f16x2*)(ep + 2 * x);
      e[2 * x] = (float)pr[0]; e[2 * x + 1] = (float)pr[1];
    }
    #pragma unroll
    for (int v = 0; v < 18; ++v)
      #pragma unroll
      for (int j = 0; j < 13; ++j)
        acc[j] = fmaf(a[v + j], e[v], acc[j]);
  }
  if (active) {
    float* o = ws + XCB + ((size_t)(br * 4096 + bc0 + bcl)) * 169 + i * 13;
    #pragma unroll
    for (int j = 0; j < 13; ++j) o[j] = acc[j];
  }
}

// ---------------- fuse v2 (validated round-8) --------------------------------
__global__ __launch_bounds__(256) void k_fuse2(float* __restrict__ ws,
                                               const float* __restrict__ fus_b,
                                               const float* __restrict__ g2,
                                               const float* __restrict__ b2,
                                               const float* __restrict__ m2,
                                               const float* __restrict__ v2,
                                               const float* __restrict__ cls_w,
                                               const float* __restrict__ cls_b,
                                               const float* __restrict__ box_w,
                                               const float* __restrict__ box_b,
                                               float* __restrict__ out) {
  const int ij0 = blockIdx.x * 13;
  const int b = blockIdx.y;
  const int br = blockIdx.z;
  const int n_out = br ? 16 : 4;
  const float* ow = br ? box_w : cls_w;
  const float* ob = br ? box_b : cls_b;
  float* outp = out + (br ? (size_t)10816 : 0);

  __shared__ float xv[256 * 13];
  __shared__ float fv[13 * 257];
  const int t = threadIdx.x;
  const float* src = ws + XCB + ((size_t)br * 4096 + b * 256) * 169;
  for (int idx = t; idx < 256 * 13; idx += 256) {
    int c = idx / 13, j = idx - c * 13;
    xv[idx] = src[(size_t)c * 169 + ij0 + j];
  }
  __syncthreads();

  const float* fwt = ws + FWT + ((size_t)br << 16) + t;
  float acc[13];
  #pragma unroll
  for (int j = 0; j < 13; ++j) acc[j] = 0.f;
  for (int c = 0; c < 256; ++c) {
    float wv = fwt[c << 8];
    #pragma unroll
    for (int j = 0; j < 13; ++j)
      acc[j] = fmaf(wv, xv[c * 13 + j], acc[j]);
  }
  float s2 = g2[br * 256 + t] * rsqrtf(v2[br * 256 + t] + EPSBN);
  float fb = fus_b[br * 256 + t], mm = m2[br * 256 + t], bb = b2[br * 256 + t];
  #pragma unroll
  for (int j = 0; j < 13; ++j)
    fv[j * 257 + t] = fmaxf((acc[j] + fb - mm) * s2 + bb, 0.f);
  __syncthreads();

  const int g = t >> 4, l16 = t & 15;
  for (int wi = g; wi < 13 * n_out; wi += 16) {
    int j = wi / n_out, po = wi - j * n_out;
    float part = 0.f;
    #pragma unroll
    for (int q = 0; q < 16; ++q)
      part = fmaf(ow[(po << 8) + l16 + (q << 4)], fv[j * 257 + l16 + (q << 4)], part);
    #pragma unroll
    for (int off = 8; off; off >>= 1) part += __shfl_xor(part, off);
    if (l16 == 0)
      outp[((size_t)b * n_out + po) * 169 + ij0 + j] = part + ob[po];
  }
}

extern "C" void kernel_launch(void* const* d_in, const int* in_sizes, int n_in,
                              void* d_out, int out_size, void* d_ws, size_t ws_size,
                              hipStream_t stream) {
  const float* ex    = (const float*)d_in[0];
  const float* inst  = (const float*)d_in[1];
  const float* off_w = (const float*)d_in[2];
  const float* off_b = (const float*)d_in[3];
  const float* dcn_w = (const float*)d_in[4];
  const float* dcn_b = (const float*)d_in[5];
  const float* bn1_g = (const float*)d_in[6];
  const float* bn1_b = (const float*)d_in[7];
  const float* bn1_m = (const float*)d_in[8];
  const float* bn1_v = (const float*)d_in[9];
  const float* fus_w = (const float*)d_in[10];
  const float* fus_b = (const float*)d_in[11];
  const float* bn2_g = (const float*)d_in[12];
  const float* bn2_b = (const float*)d_in[13];
  const float* bn2_m = (const float*)d_in[14];
  const float* bn2_v = (const float*)d_in[15];
  const float* cls_w = (const float*)d_in[16];
  const float* cls_b = (const float*)d_in[17];
  const float* box_w = (const float*)d_in[18];
  const float* box_b = (const float*)d_in[19];
  float* out = (float*)d_out;
  float* ws  = (float*)d_ws;

  _Float16* xh_ex = (_Float16*)(ws + XF_EX);
  _Float16* xh_in = (_Float16*)(ws + XF_IN);
  _Float16* wpk   = (_Float16*)(ws + WPK);
  _Float16* owpk  = (_Float16*)(ws + OWPK);

  k_transpose<<<dim3(20, 16), 256, 0, stream>>>(ex,   xh_ex, 20, 20);
  k_transpose<<<dim3(32, 16), 256, 0, stream>>>(inst, xh_in, 32, 32);
  k_wpack <<<9216, 256, 0, stream>>>(dcn_w, wpk);
  k_owpack<<<1152, 256, 0, stream>>>(off_w, owpk);
  k_fwt   <<<512, 256, 0, stream>>>(fus_w, ws + FWT);
  k_head<<<672, 512, 0, stream>>>(xh_ex, xh_in, owpk, wpk, off_b, ws,
                                  dcn_b, bn1_g, bn1_b, bn1_m, bn1_v);
  k_xcorr3<<<dim3(256, 2), 256, 0, stream>>>(ws);
  k_fuse2<<<dim3(13, 16, 2), 256, 0, stream>>>(ws, fus_b, bn2_g, bn2_b, bn2_m, bn2_v,
                                               cls_w, cls_b, box_w, box_b, out);
}

// Round 11
// 341.414 us; speedup vs baseline: 1.1318x; 1.1318x over previous
//
#include <hip/hip_runtime.h>
#include <math.h>

#define EPSBN 1e-5f

typedef _Float16 f16x8 __attribute__((ext_vector_type(8)));
typedef _Float16 f16x2 __attribute__((ext_vector_type(2)));
typedef float    f32x4 __attribute__((ext_vector_type(4)));

__device__ __forceinline__ f16x8 splat8(float v) {
  _Float16 h = (_Float16)v;
  return (f16x8){h, h, h, h, h, h, h, h};
}

// ---------------- workspace layout (float-unit offsets) — round-7 validated ---
static constexpr size_t XF_EX = 0;         // (16,20,20,256) f16
static constexpr size_t XF_IN = 819200;    // (16,32,32,256) f16
static constexpr size_t WPK   = 2916352;   // dcn_w f16 frag pack
static constexpr size_t OWPK  = 4096000;   // off_w f16 frag pack
static constexpr size_t FWT   = 4243456;   // (2,256,256) f32
static constexpr size_t OM0   = 4374528;   // (16,27,324) f32
static constexpr size_t OM1   = 4514496;   // (16,27,900)
static constexpr size_t OM2   = 4903296;
static constexpr size_t OM3   = 5043264;
static constexpr size_t HOUT0 = 5432064;   // (16,256,324) f32
static constexpr size_t HOUT1 = 6759168;   // (16,256,900) f32
static constexpr size_t HOUT2 = 10445568;
static constexpr size_t HOUT3 = 11772672;
static constexpr size_t XCB   = 15459072;  // (2,16,256,169) f32
// end 18227968 floats = 72.9 MB

// ---------------- NCHW fp32 -> NHWC f16 ----------------
__global__ __launch_bounds__(256) void k_transpose(const float* __restrict__ in,
                                                   _Float16* __restrict__ out,
                                                   int H, int W) {
  int y = blockIdx.x, b = blockIdx.y;
  __shared__ float tile[32][257];
  int t = threadIdx.x;
  int x = t & 31, cb = t >> 5;
  for (int c0 = 0; c0 < 256; c0 += 8) {
    int c = c0 + cb;
    if (x < W) tile[x][c] = in[(((size_t)b * 256 + c) * H + y) * W + x];
  }
  __syncthreads();
  for (int x2 = 0; x2 < W; ++x2)
    out[((((size_t)b * H + y) * W + x2) << 8) + t] = (_Float16)tile[x2][t];
}

// ---------------- dcn_w -> f16 MFMA-A fragment pack (validated) --------------
__global__ __launch_bounds__(256) void k_wpack(const float* __restrict__ w,
                                               _Float16* __restrict__ wp) {
  int idx = blockIdx.x * 256 + threadIdx.x;
  if (idx >= 4 * 9 * 8 * 16 * 64 * 8) return;
  int e  = idx & 7;
  int l  = (idx >> 3) & 63;
  int ot = (idx >> 9) & 15;
  int cs = (idx >> 13) & 7;
  int ht = idx >> 16;             // h*9 + tap
  int tap = ht % 9, h = ht / 9;
  int o = ot * 16 + (l & 15);
  int c = cs * 32 + 8 * (l >> 4) + e;
  wp[idx] = (_Float16)w[((size_t)((h * 256 + o) * 256 + c)) * 9 + tap];
}

// ---------------- off_w -> f16 MFMA-A fragment pack (M=27 padded to 32) ------
__global__ __launch_bounds__(256) void k_owpack(const float* __restrict__ w,
                                                _Float16* __restrict__ wp) {
  int idx = blockIdx.x * 256 + threadIdx.x;
  if (idx >= 4 * 9 * 8 * 2 * 64 * 8) return;
  int e  = idx & 7;
  int l  = (idx >> 3) & 63;
  int ot = (idx >> 9) & 1;
  int cs = (idx >> 10) & 7;
  int ht = idx >> 13;
  int tap = ht % 9, h = ht / 9;
  int o = ot * 16 + (l & 15);
  int c = cs * 32 + 8 * (l >> 4) + e;
  wp[idx] = (o < 27) ? (_Float16)w[((size_t)((h * 27 + o) * 256 + c)) * 9 + tap]
                     : (_Float16)0.f;
}

// ---------------- fus_w (2,256,256)[i][o][c] -> fwt [i][c][o] (fp32) ---------
__global__ __launch_bounds__(256) void k_fwt(const float* __restrict__ w,
                                             float* __restrict__ wt) {
  int idx = blockIdx.x * 256 + threadIdx.x;
  int o = idx & 255, c = (idx >> 8) & 255, i = idx >> 16;
  wt[idx] = w[(i << 16) + (o << 8) + c];
}

// ---------------- offset conv: direct-B MFMA, no LDS, no barriers ------------
// B-fragment of 16x16x32_f16 = per lane 8 contiguous channels of one pixel ->
// a single f16x8 global load from NHWC x at tap-shifted position.
// Per wave: 16 pixels x 32 o-rows (2 A-frags); 9 taps x 8 cs x 2 MFMA.
// Accumulation order identical to validated LDS path -> om bit-identical.
__global__ __launch_bounds__(256) void k_offdirect(const _Float16* __restrict__ xh_ex,
                                                   const _Float16* __restrict__ xh_in,
                                                   const _Float16* __restrict__ owpk,
                                                   const float* __restrict__ off_b,
                                                   float* __restrict__ ws) {
  const int h = blockIdx.z, b = blockIdx.y;
  const int HH[4] = {20, 32, 20, 32};
  const size_t OMO[4] = {OM0, OM1, OM2, OM3};
  const int H = HH[h], W = H, ho = H - 2, wo = W - 2, P = ho * wo;
  const int nblk = (P + 63) >> 6;
  if (blockIdx.x >= nblk) return;
  const int p0 = blockIdx.x << 6;
  const _Float16* xh = ((h & 1) ? xh_in : xh_ex) + (((size_t)b * H * W) << 8);

  const int t = threadIdx.x, lane = t & 63, wave = t >> 6;
  int p = min(p0 + wave * 16 + (lane & 15), P - 1);
  int i = p / wo, j = p - i * wo;
  const _Float16* xrow = xh + ((i * W + j) << 8) + 8 * (lane >> 4);

  f32x4 acc0 = {0.f, 0.f, 0.f, 0.f}, acc1 = {0.f, 0.f, 0.f, 0.f};
  for (int tap = 0; tap < 9; ++tap) {
    int ky = tap / 3, kx = tap - ky * 3;
    const _Float16* xt = xrow + ((ky * W + kx) << 8);
    const _Float16* ab0 = owpk + ((size_t)(h * 72 + tap * 8) * 2) * 512 + lane * 8;
    #pragma unroll
    for (int cs = 0; cs < 8; ++cs) {
      f16x8 bf = *(const f16x8*)(xt + cs * 32);
      f16x8 a0 = *(const f16x8*)(ab0 + (size_t)cs * 1024);
      f16x8 a1 = *(const f16x8*)(ab0 + (size_t)cs * 1024 + 512);
      acc0 = __builtin_amdgcn_mfma_f32_16x16x32_f16(a0, bf, acc0, 0, 0, 0);
      acc1 = __builtin_amdgcn_mfma_f32_16x16x32_f16(a1, bf, acc1, 0, 0, 0);
    }
  }
  float* om = ws + OMO[h] + (size_t)b * 27 * P;
  p = p0 + wave * 16 + (lane & 15);
  if (p < P) {
    #pragma unroll
    for (int r = 0; r < 4; ++r) {
      int o = 4 * (lane >> 4) + r;
      if (o < 27) om[o * P + p] = acc0[r] + off_b[h * 27 + o];
      int o2 = o + 16;
      if (o2 < 27) om[o2 * P + p] = acc1[r] + off_b[h * 27 + o2];
    }
  }
}

// ---------------- main deformable GEMM (round-7 exact, measured 86 us) -------
__global__ __launch_bounds__(256) void k_dgemm(const _Float16* __restrict__ xh_ex,
                                               const _Float16* __restrict__ xh_in,
                                               const _Float16* __restrict__ wpk,
                                               float* __restrict__ ws,
                                               const float* __restrict__ dcn_b,
                                               const float* __restrict__ g1,
                                               const float* __restrict__ b1,
                                               const float* __restrict__ m1,
                                               const float* __restrict__ v1) {
  const int h = blockIdx.z;
  const int HH4[4] = {20, 32, 20, 32};
  const size_t OMO[4] = {OM0, OM1, OM2, OM3};
  const size_t HOO[4] = {HOUT0, HOUT1, HOUT2, HOUT3};
  const int H = HH4[h], W = H, ho = H - 2, wo = W - 2, P = ho * wo;
  const int nblk = (P + 63) >> 6;
  if (blockIdx.x >= nblk) return;
  const int b = blockIdx.y;
  const int p0 = blockIdx.x << 6;
  const _Float16* xh = (h & 1) ? xh_in : xh_ex;
  const float* om = ws + OMO[h] + (size_t)b * 27 * P;
  float* outp = ws + HOO[h] + (size_t)b * 256 * P;

  __shared__ float4 swt4[576];
  __shared__ int4   sad4[576];
  __shared__ __align__(16) _Float16 S[64 * 256];

  const int t = threadIdx.x, lane = t & 63, wave = t >> 6;

  // Phase A: per-(pixel,tap) bilinear weights (mask+validity folded) & addrs
  for (int e = t; e < 576; e += 256) {
    int pl = e / 9, k = e - pl * 9;
    float w4[4] = {0.f, 0.f, 0.f, 0.f};
    int a4[4] = {0, 0, 0, 0};
    int p = p0 + pl;
    if (p < P) {
      int i = p / wo, j = p - i * wo;
      float oy = om[(2 * k) * P + p];
      float ox = om[(2 * k + 1) * P + p];
      float mm = om[(18 + k) * P + p];
      float msk = 1.f / (1.f + __expf(-mm));
      int ky = k / 3, kx = k - ky * 3;
      float py = (float)(ky + i) + oy;
      float px = (float)(kx + j) + ox;
      float fy = floorf(py), fx = floorf(px);
      int y0 = (int)fy, x0 = (int)fx;
      float dy = py - fy, dx = px - fx;
      #pragma unroll
      for (int q = 0; q < 4; ++q) {
        int yy = y0 + (q >> 1), xx = x0 + (q & 1);
        bool vld = (yy >= 0) && (yy < H) && (xx < W) && (xx >= 0);
        int yc = min(max(yy, 0), H - 1), xc = min(max(xx, 0), W - 1);
        float wq = ((q >> 1) ? dy : 1.f - dy) * ((q & 1) ? dx : 1.f - dx);
        w4[q] = vld ? wq * msk : 0.f;
        a4[q] = ((blockIdx.y * H + yc) * W + xc) << 8;
      }
    }
    swt4[e] = make_float4(w4[0], w4[1], w4[2], w4[3]);
    sad4[e] = make_int4(a4[0], a4[1], a4[2], a4[3]);
  }

  f32x4 acc[4][4];
  #pragma unroll
  for (int a = 0; a < 4; ++a)
    #pragma unroll
    for (int n = 0; n < 4; ++n) acc[a][n] = (f32x4){0.f, 0.f, 0.f, 0.f};

  __syncthreads();

  const int o8 = t & 31;
  for (int tap = 0; tap < 9; ++tap) {
    // Phase B: sample 64p x 256c f16 into swizzled LDS
    #pragma unroll
    for (int it = 0; it < 8; ++it) {
      int pl = it * 8 + (t >> 5);
      float4 w4 = swt4[pl * 9 + tap];
      int4   a4 = sad4[pl * 9 + tap];
      const _Float16* xb = xh + o8 * 8;
      f16x8 x0 = *(const f16x8*)(xb + a4.x);
      f16x8 x1 = *(const f16x8*)(xb + a4.y);
      f16x8 x2 = *(const f16x8*)(xb + a4.z);
      f16x8 x3 = *(const f16x8*)(xb + a4.w);
      f16x8 s = x0 * splat8(w4.x) + x1 * splat8(w4.y) + x2 * splat8(w4.z) + x3 * splat8(w4.w);
      *(f16x8*)((char*)S + pl * 512 + ((o8 * 16) ^ ((pl & 7) << 4))) = s;
    }
    __syncthreads();
    // Phase C: 8 K-steps x (4 otile x 4 ptile) MFMA
    #pragma unroll
    for (int cs = 0; cs < 8; ++cs) {
      int ksg = tap * 8 + cs;
      const _Float16* ab = wpk + ((size_t)(h * 72 + ksg) * 16 + wave * 4) * 512 + lane * 8;
      f16x8 A0 = *(const f16x8*)(ab);
      f16x8 A1 = *(const f16x8*)(ab + 512);
      f16x8 A2 = *(const f16x8*)(ab + 1024);
      f16x8 A3 = *(const f16x8*)(ab + 1536);
      f16x8 B[4];
      #pragma unroll
      for (int n = 0; n < 4; ++n) {
        int prow = n * 16 + (lane & 15);
        B[n] = *(const f16x8*)((char*)S + prow * 512 +
                               ((cs * 64 + ((lane >> 4) << 4)) ^ ((prow & 7) << 4)));
      }
      #pragma unroll
      for (int n = 0; n < 4; ++n) {
        acc[0][n] = __builtin_amdgcn_mfma_f32_16x16x32_f16(A0, B[n], acc[0][n], 0, 0, 0);
        acc[1][n] = __builtin_amdgcn_mfma_f32_16x16x32_f16(A1, B[n], acc[1][n], 0, 0, 0);
        acc[2][n] = __builtin_amdgcn_mfma_f32_16x16x32_f16(A2, B[n], acc[2][n], 0, 0, 0);
        acc[3][n] = __builtin_amdgcn_mfma_f32_16x16x32_f16(A3, B[n], acc[3][n], 0, 0, 0);
      }
    }
    __syncthreads();
  }

  // epilogue: + dcn_b then bn1; out layout (B,256o,P) fp32 (validated)
  #pragma unroll
  for (int a = 0; a < 4; ++a) {
    int obase = (wave * 4 + a) * 16 + 4 * (lane >> 4);
    #pragma unroll
    for (int r = 0; r < 4; ++r) {
      int o = obase + r;
      float al = g1[h * 256 + o] * rsqrtf(v1[h * 256 + o] + EPSBN);
      float be = (dcn_b[h * 256 + o] - m1[h * 256 + o]) * al + b1[h * 256 + o];
      #pragma unroll
      for (int n = 0; n < 4; ++n) {
        int p = p0 + n * 16 + (lane & 15);
        if (p < P) outp[(size_t)o * P + p] = fmaf(acc[a][n][r], al, be);
      }
    }
  }
}

// ---------------- xcorr v3 (validated round-7) -------------------------------
__global__ __launch_bounds__(256) void k_xcorr3(float* __restrict__ ws) {
  const int br = blockIdx.y;
  const int bc0 = blockIdx.x << 4;
  const float* exg = ws + (br ? HOUT2 : HOUT0) + (size_t)bc0 * 324;
  const float* ing = ws + (br ? HOUT3 : HOUT1) + (size_t)bc0 * 900;
  __shared__ __align__(16) _Float16 exl[16 * 324];
  __shared__ __align__(16) _Float16 inl[16 * 960];   // rows padded 30 -> 32
  const int t = threadIdx.x;
  for (int idx = t; idx < 16 * 324; idx += 256)
    exl[idx] = (_Float16)exg[idx];
  for (int idx = t; idx < 16 * 960; idx += 256) {
    int c = idx & 31;
    int rr = idx >> 5;
    inl[idx] = (c < 30) ? (_Float16)ing[rr * 30 + c] : (_Float16)0.f;
  }
  __syncthreads();
  const int lane = t & 63, wave = t >> 6;
  const int sub = lane / 13;
  const int i = lane - sub * 13;
  const bool active = sub < 4;
  const int bcl = wave * 4 + (active ? sub : 0);
  float acc[13];
  #pragma unroll
  for (int j = 0; j < 13; ++j) acc[j] = 0.f;
  const _Float16* inb = inl + bcl * 960;
  const _Float16* exb = exl + bcl * 324;
  for (int u = 0; u < 18; ++u) {
    float a[30];
    const _Float16* rp = inb + (i + u) * 32;
    #pragma unroll
    for (int x = 0; x < 15; ++x) {
      f16x2 pr = *(const f16x2*)(rp + 2 * x);
      a[2 * x] = (float)pr[0]; a[2 * x + 1] = (float)pr[1];
    }
    float e[18];
    const _Float16* ep = exb + u * 18;
    #pragma unroll
    for (int x = 0; x < 9; ++x) {
      f16x2 pr = *(const f16x2*)(ep + 2 * x);
      e[2 * x] = (float)pr[0]; e[2 * x + 1] = (float)pr[1];
    }
    #pragma unroll
    for (int v = 0; v < 18; ++v)
      #pragma unroll
      for (int j = 0; j < 13; ++j)
        acc[j] = fmaf(a[v + j], e[v], acc[j]);
  }
  if (active) {
    float* o = ws + XCB + ((size_t)(br * 4096 + bc0 + bcl)) * 169 + i * 13;
    #pragma unroll
    for (int j = 0; j < 13; ++j) o[j] = acc[j];
  }
}

// ---------------- fuse v2 (validated round-8) --------------------------------
__global__ __launch_bounds__(256) void k_fuse2(float* __restrict__ ws,
                                               const float* __restrict__ fus_b,
                                               const float* __restrict__ g2,
                                               const float* __restrict__ b2,
                                               const float* __restrict__ m2,
                                               const float* __restrict__ v2,
                                               const float* __restrict__ cls_w,
                                               const float* __restrict__ cls_b,
                                               const float* __restrict__ box_w,
                                               const float* __restrict__ box_b,
                                               float* __restrict__ out) {
  const int ij0 = blockIdx.x * 13;
  const int b = blockIdx.y;
  const int br = blockIdx.z;
  const int n_out = br ? 16 : 4;
  const float* ow = br ? box_w : cls_w;
  const float* ob = br ? box_b : cls_b;
  float* outp = out + (br ? (size_t)10816 : 0);

  __shared__ float xv[256 * 13];
  __shared__ float fv[13 * 257];
  const int t = threadIdx.x;
  const float* src = ws + XCB + ((size_t)br * 4096 + b * 256) * 169;
  for (int idx = t; idx < 256 * 13; idx += 256) {
    int c = idx / 13, j = idx - c * 13;
    xv[idx] = src[(size_t)c * 169 + ij0 + j];
  }
  __syncthreads();

  const float* fwt = ws + FWT + ((size_t)br << 16) + t;
  float acc[13];
  #pragma unroll
  for (int j = 0; j < 13; ++j) acc[j] = 0.f;
  for (int c = 0; c < 256; ++c) {
    float wv = fwt[c << 8];
    #pragma unroll
    for (int j = 0; j < 13; ++j)
      acc[j] = fmaf(wv, xv[c * 13 + j], acc[j]);
  }
  float s2 = g2[br * 256 + t] * rsqrtf(v2[br * 256 + t] + EPSBN);
  float fb = fus_b[br * 256 + t], mm = m2[br * 256 + t], bb = b2[br * 256 + t];
  #pragma unroll
  for (int j = 0; j < 13; ++j)
    fv[j * 257 + t] = fmaxf((acc[j] + fb - mm) * s2 + bb, 0.f);
  __syncthreads();

  const int g = t >> 4, l16 = t & 15;
  for (int wi = g; wi < 13 * n_out; wi += 16) {
    int j = wi / n_out, po = wi - j * n_out;
    float part = 0.f;
    #pragma unroll
    for (int q = 0; q < 16; ++q)
      part = fmaf(ow[(po << 8) + l16 + (q << 4)], fv[j * 257 + l16 + (q << 4)], part);
    #pragma unroll
    for (int off = 8; off; off >>= 1) part += __shfl_xor(part, off);
    if (l16 == 0)
      outp[((size_t)b * n_out + po) * 169 + ij0 + j] = part + ob[po];
  }
}

extern "C" void kernel_launch(void* const* d_in, const int* in_sizes, int n_in,
                              void* d_out, int out_size, void* d_ws, size_t ws_size,
                              hipStream_t stream) {
  const float* ex    = (const float*)d_in[0];
  const float* inst  = (const float*)d_in[1];
  const float* off_w = (const float*)d_in[2];
  const float* off_b = (const float*)d_in[3];
  const float* dcn_w = (const float*)d_in[4];
  const float* dcn_b = (const float*)d_in[5];
  const float* bn1_g = (const float*)d_in[6];
  const float* bn1_b = (const float*)d_in[7];
  const float* bn1_m = (const float*)d_in[8];
  const float* bn1_v = (const float*)d_in[9];
  const float* fus_w = (const float*)d_in[10];
  const float* fus_b = (const float*)d_in[11];
  const float* bn2_g = (const float*)d_in[12];
  const float* bn2_b = (const float*)d_in[13];
  const float* bn2_m = (const float*)d_in[14];
  const float* bn2_v = (const float*)d_in[15];
  const float* cls_w = (const float*)d_in[16];
  const float* cls_b = (const float*)d_in[17];
  const float* box_w = (const float*)d_in[18];
  const float* box_b = (const float*)d_in[19];
  float* out = (float*)d_out;
  float* ws  = (float*)d_ws;

  _Float16* xh_ex = (_Float16*)(ws + XF_EX);
  _Float16* xh_in = (_Float16*)(ws + XF_IN);
  _Float16* wpk   = (_Float16*)(ws + WPK);
  _Float16* owpk  = (_Float16*)(ws + OWPK);

  k_transpose<<<dim3(20, 16), 256, 0, stream>>>(ex,   xh_ex, 20, 20);
  k_transpose<<<dim3(32, 16), 256, 0, stream>>>(inst, xh_in, 32, 32);
  k_wpack <<<9216, 256, 0, stream>>>(dcn_w, wpk);
  k_owpack<<<1152, 256, 0, stream>>>(off_w, owpk);
  k_fwt   <<<512, 256, 0, stream>>>(fus_w, ws + FWT);
  k_offdirect<<<dim3(15, 16, 4), 256, 0, stream>>>(xh_ex, xh_in, owpk, off_b, ws);
  k_dgemm<<<dim3(15, 16, 4), 256, 0, stream>>>(xh_ex, xh_in, wpk, ws,
                                               dcn_b, bn1_g, bn1_b, bn1_m, bn1_v);
  k_xcorr3<<<dim3(256, 2), 256, 0, stream>>>(ws);
  k_fuse2<<<dim3(13, 16, 2), 256, 0, stream>>>(ws, fus_b, bn2_g, bn2_b, bn2_m, bn2_v,
                                               cls_w, cls_b, box_w, box_b, out);
}